// Round 1
// baseline (648.905 us; speedup 1.0000x reference)
//
#include <hip/hip_runtime.h>

// Problem constants
#define NB 8
#define NC 128
#define NS 128
#define NE 128
#define NH 8
#define NP 16
#define BSROWS (NB*NS)            // 1024
#define NROWS  (NB*NC*NS)         // 131072
#define CHUNK  (BSROWS*NH*NC*NP)  // 16,777,216 floats per q/k/v/o buffer

// ---------------------------------------------------------------------------
// Kernel 1: K/V projection.  k[b,s,h,c,p] = sum_e x[b,c,s,e] * Wk[h,e,p]
// One block = 64 consecutive x rows (row = (b*C+c)*S+s). Output written in
// attention layout: [(b*S+s)*H + h][c][p]  (chunk of C*P=2048 floats).
// ---------------------------------------------------------------------------
__global__ __launch_bounds__(256) void kv_kernel(
    const float* __restrict__ x, const float* __restrict__ Wk,
    const float* __restrict__ Wv, float* __restrict__ kb, float* __restrict__ vb)
{
    __shared__ float xt[64][128];
    const int tid  = threadIdx.x;
    const int row0 = blockIdx.x * 64;
    {
        const float4* xg = (const float4*)(x + (size_t)row0 * 128);
        float4* xs = (float4*)(&xt[0][0]);
        #pragma unroll
        for (int i = 0; i < 8; ++i) xs[i*256 + tid] = xg[i*256 + tid];
    }
    __syncthreads();
    const int lane = tid & 63;
    const int w    = tid >> 6;
    const int h0   = lane >> 4;   // head for col j=lane (cols 0..63)
    const int p    = lane & 15;
    const float* pk0 = Wk + h0*(NE*NP) + p;        // element e at [e*NP]
    const float* pk1 = Wk + (h0+4)*(NE*NP) + p;    // col j+64 -> head h0+4
    const float* pv0 = Wv + h0*(NE*NP) + p;
    const float* pv1 = Wv + (h0+4)*(NE*NP) + p;
    float aK0[16]={}, aK1[16]={}, aV0[16]={}, aV1[16]={};
    for (int e = 0; e < 128; e += 4) {
        float wk0[4], wk1[4], wv0[4], wv1[4];
        #pragma unroll
        for (int u = 0; u < 4; ++u) {
            wk0[u] = pk0[(e+u)*NP]; wk1[u] = pk1[(e+u)*NP];
            wv0[u] = pv0[(e+u)*NP]; wv1[u] = pv1[(e+u)*NP];
        }
        #pragma unroll
        for (int r = 0; r < 16; ++r) {
            float4 xv = *(const float4*)(&xt[w + r*4][e]);   // broadcast read
            float xa[4] = {xv.x, xv.y, xv.z, xv.w};
            #pragma unroll
            for (int u = 0; u < 4; ++u) {
                aK0[r] += xa[u]*wk0[u];
                aK1[r] += xa[u]*wk1[u];
                aV0[r] += xa[u]*wv0[u];
                aV1[r] += xa[u]*wv1[u];
            }
        }
    }
    #pragma unroll
    for (int r = 0; r < 16; ++r) {
        int gr = row0 + w + r*4;            // = b*16384 + c*128 + s
        int b  = gr >> 14;
        int c  = (gr >> 7) & (NC-1);
        int s  = gr & (NS-1);
        int bs = b*NS + s;
        int base0 = (bs*NH + h0    )*(NC*NP) + c*NP + p;
        int base1 = (bs*NH + h0 + 4)*(NC*NP) + c*NP + p;
        kb[base0] = aK0[r]; kb[base1] = aK1[r];
        vb[base0] = aV0[r]; vb[base1] = aV1[r];
    }
}

// ---------------------------------------------------------------------------
// Kernel 2: Q projection (per-joint weights).
// q[b,s,h,c,p] = sum_e x[b,c,s,e] * Wq[h,c,p,e]
// grid = (BS/64 tiles, C). For fixed c, 64 consecutive (b,s) rows of x are
// contiguous in memory (tile never crosses a b boundary since 64 | S).
// ---------------------------------------------------------------------------
__global__ __launch_bounds__(256) void q_kernel(
    const float* __restrict__ x, const float* __restrict__ Wq, float* __restrict__ qb)
{
    __shared__ float xt[64][128];
    const int tid  = threadIdx.x;
    const int c    = blockIdx.y;
    const int row0 = blockIdx.x * 64;       // in (b*S+s) space
    const int b0   = row0 >> 7;
    const int s0   = row0 & (NS-1);
    const size_t gbase = ((size_t)(b0*NC + c)*NS + s0) * NE;
    {
        const float4* xg = (const float4*)(x + gbase);
        float4* xs = (float4*)(&xt[0][0]);
        #pragma unroll
        for (int i = 0; i < 8; ++i) xs[i*256 + tid] = xg[i*256 + tid];
    }
    __syncthreads();
    const int lane = tid & 63;
    const int w    = tid >> 6;
    const int h0   = lane >> 4;
    const int p    = lane & 15;
    const float* pq0 = Wq + (size_t)h0*(NC*NP*NE) + c*(NP*NE) + p*NE;  // contiguous in e
    const float* pq1 = pq0 + (size_t)4*(NC*NP*NE);
    float a0[16]={}, a1[16]={};
    for (int e = 0; e < 128; e += 4) {
        float4 w0 = *(const float4*)(pq0 + e);
        float4 w1 = *(const float4*)(pq1 + e);
        float wa0[4]={w0.x,w0.y,w0.z,w0.w}, wa1[4]={w1.x,w1.y,w1.z,w1.w};
        #pragma unroll
        for (int r = 0; r < 16; ++r) {
            float4 xv = *(const float4*)(&xt[w + r*4][e]);
            float xa[4]={xv.x,xv.y,xv.z,xv.w};
            #pragma unroll
            for (int u = 0; u < 4; ++u) { a0[r] += xa[u]*wa0[u]; a1[r] += xa[u]*wa1[u]; }
        }
    }
    #pragma unroll
    for (int r = 0; r < 16; ++r) {
        int bs = row0 + w + r*4;
        int base0 = (bs*NH + h0    )*(NC*NP) + c*NP + p;
        int base1 = (bs*NH + h0 + 4)*(NC*NP) + c*NP + p;
        qb[base0] = a0[r]; qb[base1] = a1[r];
    }
}

// ---------------------------------------------------------------------------
// Kernel 3: attention over the joint axis. One block per (b,s,h).
// scores[c,d] = (q[c,:].k[d,:])/4 ; softmax over d ; o[c,p] = sum_d a[c,d]v[d,p]
// A-matrix handled in two 64-row halves -> LDS = 61.7 KB (2 blocks/CU).
// o written directly in [B,C,S,E] layout (e = h*16+p).
// ---------------------------------------------------------------------------
__global__ __launch_bounds__(256) void attn_kernel(
    const float* __restrict__ qb, const float* __restrict__ kb,
    const float* __restrict__ vb, float* __restrict__ ob)
{
    __shared__ float qs[128][17];   // padded: conflict-free strided-row reads
    __shared__ float ks[128][17];
    __shared__ float vs[128][20];   // 16B-aligned rows for float4 reads
    __shared__ float As[64][133];   // stride 133: conflict-free PV broadcast
    const int tid = threadIdx.x;
    const int idx = blockIdx.x;                 // = (b*S+s)*H + h
    const size_t base = (size_t)idx * (NC*NP);
    #pragma unroll
    for (int i = 0; i < 2; ++i) {
        int f4 = i*256 + tid;
        int d = f4 >> 2, pp = (f4 & 3) * 4;
        float4 tq = *(const float4*)(qb + base + f4*4);
        qs[d][pp]=tq.x; qs[d][pp+1]=tq.y; qs[d][pp+2]=tq.z; qs[d][pp+3]=tq.w;
        float4 tk = *(const float4*)(kb + base + f4*4);
        ks[d][pp]=tk.x; ks[d][pp+1]=tk.y; ks[d][pp+2]=tk.z; ks[d][pp+3]=tk.w;
        float4 tv = *(const float4*)(vb + base + f4*4);
        vs[d][pp]=tv.x; vs[d][pp+1]=tv.y; vs[d][pp+2]=tv.z; vs[d][pp+3]=tv.w;
    }
    __syncthreads();
    const int ty = tid >> 4, tx = tid & 15;
    const int h  = idx & (NH-1);
    const int bs = idx >> 3;
    const int b  = bs >> 7, s = bs & (NS-1);

    for (int half = 0; half < 2; ++half) {
        // ---- scores: rows c = half*64 + ty + 16r (r<4), cols d = tx + 16k ----
        float sc[4][8];
        #pragma unroll
        for (int r = 0; r < 4; ++r)
            #pragma unroll
            for (int k = 0; k < 8; ++k) sc[r][k] = 0.f;
        for (int pp = 0; pp < 16; ++pp) {
            float qv[4], kv[8];
            #pragma unroll
            for (int r = 0; r < 4; ++r) qv[r] = qs[half*64 + ty + 16*r][pp];
            #pragma unroll
            for (int k = 0; k < 8; ++k) kv[k] = ks[tx + 16*k][pp];
            #pragma unroll
            for (int r = 0; r < 4; ++r)
                #pragma unroll
                for (int k = 0; k < 8; ++k) sc[r][k] += qv[r]*kv[k];
        }
        // ---- softmax along d (each row owned by 16 lanes sharing ty) ----
        #pragma unroll
        for (int r = 0; r < 4; ++r) {
            float m = -1e30f;
            #pragma unroll
            for (int k = 0; k < 8; ++k) { sc[r][k] *= 0.25f; m = fmaxf(m, sc[r][k]); }
            #pragma unroll
            for (int o = 1; o < 16; o <<= 1) m = fmaxf(m, __shfl_xor(m, o));
            float sum = 0.f;
            #pragma unroll
            for (int k = 0; k < 8; ++k) { sc[r][k] = __expf(sc[r][k] - m); sum += sc[r][k]; }
            #pragma unroll
            for (int o = 1; o < 16; o <<= 1) sum += __shfl_xor(sum, o);
            float inv = 1.0f / sum;
            #pragma unroll
            for (int k = 0; k < 8; ++k) As[ty + 16*r][tx + 16*k] = sc[r][k] * inv;
        }
        __syncthreads();
        // ---- PV: one output row per thread: c = half*64 + (tid>>2), p4 = (tid&3)*4
        const int p4 = (tid & 3) * 4;
        const int cr = tid >> 2;
        float o0[4] = {0.f,0.f,0.f,0.f};
        for (int d = 0; d < 128; ++d) {
            float4 vv = *(const float4*)(&vs[d][p4]);
            float a0 = As[cr][d];
            o0[0] += a0*vv.x; o0[1] += a0*vv.y; o0[2] += a0*vv.z; o0[3] += a0*vv.w;
        }
        int c = half*64 + cr;
        size_t obase = ((size_t)(b*NC + c)*NS + s)*NE + h*NP + p4;
        *(float4*)(ob + obase) = make_float4(o0[0], o0[1], o0[2], o0[3]);
        __syncthreads();   // As reused next half
    }
}

// ---------------------------------------------------------------------------
// Kernel 4: per-joint output mixing. out[b,c,s,f] = sum_e o[b,c,s,e]*Wo[c,e,f]
// ---------------------------------------------------------------------------
__global__ __launch_bounds__(256) void out_kernel(
    const float* __restrict__ ob, const float* __restrict__ Wo, float* __restrict__ out)
{
    __shared__ float ot[64][128];
    const int tid  = threadIdx.x;
    const int c    = blockIdx.y;
    const int row0 = blockIdx.x * 64;
    const int b0   = row0 >> 7;
    const int s0   = row0 & (NS-1);
    const size_t gbase = ((size_t)(b0*NC + c)*NS + s0) * NE;
    {
        const float4* xg = (const float4*)(ob + gbase);
        float4* xs = (float4*)(&ot[0][0]);
        #pragma unroll
        for (int i = 0; i < 8; ++i) xs[i*256 + tid] = xg[i*256 + tid];
    }
    __syncthreads();
    const int lane = tid & 63;
    const int w    = tid >> 6;
    const float* pw0 = Wo + (size_t)c*(NE*NE) + lane;   // element e at [e*NE]
    const float* pw1 = pw0 + 64;
    float a0[16]={}, a1[16]={};
    for (int e = 0; e < 128; e += 4) {
        float w0[4], w1[4];
        #pragma unroll
        for (int u = 0; u < 4; ++u) { w0[u] = pw0[(e+u)*NE]; w1[u] = pw1[(e+u)*NE]; }
        #pragma unroll
        for (int r = 0; r < 16; ++r) {
            float4 xv = *(const float4*)(&ot[w + r*4][e]);
            float xa[4]={xv.x,xv.y,xv.z,xv.w};
            #pragma unroll
            for (int u = 0; u < 4; ++u) { a0[r] += xa[u]*w0[u]; a1[r] += xa[u]*w1[u]; }
        }
    }
    float* orow = out + gbase;
    #pragma unroll
    for (int r = 0; r < 16; ++r) {
        int rr = w + r*4;
        orow[(size_t)rr*NE + lane]      = a0[r];
        orow[(size_t)rr*NE + lane + 64] = a1[r];
    }
}

// Sentinel: unambiguous signal that ws_size was too small.
__global__ void sentinel_kernel(float* out, int n) {
    int i = blockIdx.x * 256 + threadIdx.x;
    if (i < n) out[i] = 1.0e6f;
}

extern "C" void kernel_launch(void* const* d_in, const int* in_sizes, int n_in,
                              void* d_out, int out_size, void* d_ws, size_t ws_size,
                              hipStream_t stream)
{
    const float* x  = (const float*)d_in[0];
    const float* Wq = (const float*)d_in[1];
    const float* Wk = (const float*)d_in[2];
    const float* Wv = (const float*)d_in[3];
    const float* Wo = (const float*)d_in[4];
    float* out = (float*)d_out;
    float* ws  = (float*)d_ws;

    if (ws_size < (size_t)4 * CHUNK * sizeof(float)) {
        sentinel_kernel<<<(out_size + 255)/256, 256, 0, stream>>>(out, out_size);
        return;
    }
    float* qbuf = ws;
    float* kbuf = ws + (size_t)CHUNK;
    float* vbuf = ws + (size_t)2*CHUNK;
    float* obuf = ws + (size_t)3*CHUNK;

    kv_kernel  <<<NROWS/64, 256, 0, stream>>>(x, Wk, Wv, kbuf, vbuf);
    q_kernel   <<<dim3(BSROWS/64, NC), 256, 0, stream>>>(x, Wq, qbuf);
    attn_kernel<<<BSROWS*NH, 256, 0, stream>>>(qbuf, kbuf, vbuf, obuf);
    out_kernel <<<dim3(BSROWS/64, NC), 256, 0, stream>>>(obuf, Wo, out);
}

// Round 3
// 508.981 us; speedup vs baseline: 1.2749x; 1.2749x over previous
//
#include <hip/hip_runtime.h>

typedef unsigned int uint;
typedef unsigned short ushort;

// Problem constants
#define NB 8
#define NC 128
#define NS 128
#define NE 128
#define NH 8
#define NP 16
#define BSROWS (NB*NS)            // 1024
#define NROWS  (NB*NC*NS)         // 131072
#define CHUNK  (BSROWS*NH*NC*NP)  // 16,777,216 elems per q/k/v/o buffer
#define WQ_ELEMS 2097152          // 8*128*16*128
#define WO_ELEMS 2097152          // 128*128*128
#define WKV_ELEMS 16384           // 8*128*16

using bf16x8 = __attribute__((ext_vector_type(8))) short;
using f32x4  = __attribute__((ext_vector_type(4))) float;

__device__ __forceinline__ f32x4 mfma16(bf16x8 a, bf16x8 b, f32x4 c) {
    return __builtin_amdgcn_mfma_f32_16x16x32_bf16(a, b, c, 0, 0, 0);
}

// f32 -> (bf16 hi, bf16 lo) split: hi = RNE(f), lo = trunc(f - hi).
__device__ __forceinline__ void cvt_hilo(float f, uint& h, uint& l) {
    uint u  = __float_as_uint(f);
    uint hh = (u + 0x7FFFu + ((u >> 16) & 1u)) >> 16;   // RNE to bf16
    float r = f - __uint_as_float(hh << 16);            // exact
    h = hh;
    l = __float_as_uint(r) >> 16;                       // truncate (fine for lo)
}
__device__ __forceinline__ void cvt2(float f0, float f1, uint& hp, uint& lp) {
    uint h0, l0, h1, l1;
    cvt_hilo(f0, h0, l0); cvt_hilo(f1, h1, l1);
    hp = h0 | (h1 << 16); lp = l0 | (l1 << 16);
}

// ---------------------------------------------------------------------------
// LDS A-tile: 64 rows x 128 k, bf16 hi/lo planes, XOR-swizzled 16B chunks
// (byte ^= (row&7)<<4) -> ds_read_b128 fragment reads are 2-way (free).
// ---------------------------------------------------------------------------
__device__ __forceinline__ void stageA_f32(const float* __restrict__ src,
                                           ushort* Ahi, ushort* Alo, int tid) {
    #pragma unroll
    for (int i = 0; i < 4; ++i) {
        int f8  = i * 256 + tid;      // 8-elem chunk id, 1024 total
        int row = f8 >> 4;
        int kc  = f8 & 15;
        const float* rp = src + row * 128 + kc * 8;
        float4 v0 = *(const float4*)rp;
        float4 v1 = *(const float4*)(rp + 4);
        uint h0,l0,h1,l1,h2,l2,h3,l3;
        cvt2(v0.x, v0.y, h0, l0); cvt2(v0.z, v0.w, h1, l1);
        cvt2(v1.x, v1.y, h2, l2); cvt2(v1.z, v1.w, h3, l3);
        int off = row * 256 + ((kc * 16) ^ ((row & 7) << 4));
        *(uint4*)((char*)Ahi + off) = make_uint4(h0, h1, h2, h3);
        *(uint4*)((char*)Alo + off) = make_uint4(l0, l1, l2, l3);
    }
}

__device__ __forceinline__ void stageA_bf16(const ushort* __restrict__ hsrc,
                                            const ushort* __restrict__ lsrc,
                                            ushort* Ahi, ushort* Alo, int tid) {
    #pragma unroll
    for (int i = 0; i < 4; ++i) {
        int f8  = i * 256 + tid;
        int row = f8 >> 4;
        int kc  = f8 & 15;
        uint4 hv = *(const uint4*)((const char*)hsrc + (size_t)(row * 128 + kc * 8) * 2);
        uint4 lv = *(const uint4*)((const char*)lsrc + (size_t)(row * 128 + kc * 8) * 2);
        int off = row * 256 + ((kc * 16) ^ ((row & 7) << 4));
        *(uint4*)((char*)Ahi + off) = hv;
        *(uint4*)((char*)Alo + off) = lv;
    }
}

// A-fragment read: lane holds A[row = mt*16 + (l&15)][k = kk*32 + (l>>4)*8 + 0..7]
__device__ __forceinline__ bf16x8 ldA(const ushort* A, int mt, int kk, int lane) {
    int row = mt * 16 + (lane & 15);
    int kb  = kk * 64 + ((lane >> 4) << 4);   // byte offset within row
    int off = row * 256 + (kb ^ ((row & 7) << 4));
    return *(const bf16x8*)((const char*)A + off);
}

// ---------------------------------------------------------------------------
// Weight packing (re-run every launch; buffers alias dead ws phases)
// ---------------------------------------------------------------------------
__global__ __launch_bounds__(256) void pack_linear(
    const float* __restrict__ src, ushort* __restrict__ dh, ushort* __restrict__ dl, int n4)
{
    int i = blockIdx.x * 256 + threadIdx.x;
    if (i >= n4) return;
    float4 v = ((const float4*)src)[i];
    uint h0,l0,h1,l1;
    cvt2(v.x, v.y, h0, l0); cvt2(v.z, v.w, h1, l1);
    ((uint2*)dh)[i] = make_uint2(h0, h1);
    ((uint2*)dl)[i] = make_uint2(l0, l1);
}

// Wk/Wv [h,e,p] -> [h*16+p][e]
__global__ __launch_bounds__(256) void pack_kvw(
    const float* __restrict__ src, ushort* __restrict__ dh, ushort* __restrict__ dl)
{
    int idx = blockIdx.x * 256 + threadIdx.x;    // 16384
    int hp = idx >> 7, e = idx & 127;
    int h = hp >> 4, p = hp & 15;
    float v = src[(h * 128 + e) * 16 + p];
    uint hh, ll; cvt_hilo(v, hh, ll);
    dh[idx] = (ushort)hh; dl[idx] = (ushort)ll;
}

// Wo [c,e,f] -> [c*128+f][e] via LDS transpose (coalesced both sides)
__global__ __launch_bounds__(256) void pack_wo(
    const float* __restrict__ Wo, ushort* __restrict__ dh, ushort* __restrict__ dl)
{
    __shared__ float t[32][129];
    const int tid = threadIdx.x;
    const int c = blockIdx.y, ec = blockIdx.x * 32;
    #pragma unroll
    for (int i = 0; i < 16; ++i) {
        int idx = i * 256 + tid;                 // 4096 = 32*128
        int e = idx >> 7, f = idx & 127;
        t[e][f] = Wo[((size_t)(c * 128) + ec + e) * 128 + f];
    }
    __syncthreads();
    #pragma unroll
    for (int i = 0; i < 8; ++i) {
        int o2 = i * 256 + tid;                  // 2048 pairs
        int f = o2 >> 4, e2 = o2 & 15;
        uint hh, ll;
        cvt2(t[2 * e2][f], t[2 * e2 + 1][f], hh, ll);
        size_t oo = ((size_t)(c * 128 + f)) * 128 + ec + 2 * e2;   // even
        *(uint*)((char*)dh + oo * 2) = hh;
        *(uint*)((char*)dl + oo * 2) = ll;
    }
}

// ---------------------------------------------------------------------------
// K/V projection, split-bf16 MFMA. Block = 64 x rows, N=256 (K cols | V cols).
// ---------------------------------------------------------------------------
__global__ __launch_bounds__(256) void kv_mfma(
    const float* __restrict__ x,
    const ushort* __restrict__ wkhi, const ushort* __restrict__ wklo,
    const ushort* __restrict__ wvhi, const ushort* __restrict__ wvlo,
    float* __restrict__ kb, float* __restrict__ vb)
{
    __shared__ __align__(16) ushort Ahi[64 * 128];
    __shared__ __align__(16) ushort Alo[64 * 128];
    const int tid  = threadIdx.x;
    const int row0 = blockIdx.x * 64;
    stageA_f32(x + (size_t)row0 * 128, Ahi, Alo, tid);
    __syncthreads();

    const int lane = tid & 63;
    const int w    = tid >> 6;
    const ushort* bhp = (w >> 1) ? wvhi : wkhi;
    const ushort* blp = (w >> 1) ? wvlo : wklo;
    float* ob = (w >> 1) ? vb : kb;
    const int nb   = (w & 1) * 64;
    const int bcol = lane & 15;
    const int bkg  = (lane >> 4) * 8;

    f32x4 zed; zed[0]=0.f; zed[1]=0.f; zed[2]=0.f; zed[3]=0.f;
    f32x4 acc[4][4];
    #pragma unroll
    for (int i = 0; i < 4; ++i)
        #pragma unroll
        for (int j = 0; j < 4; ++j) acc[i][j] = zed;

    #pragma unroll
    for (int kk = 0; kk < 4; ++kk) {
        bf16x8 Bh[4], Bl[4];
        #pragma unroll
        for (int j = 0; j < 4; ++j) {
            int n = nb + j * 16 + bcol;
            size_t eo = (size_t)n * 128 + kk * 32 + bkg;
            Bh[j] = *(const bf16x8*)(bhp + eo);
            Bl[j] = *(const bf16x8*)(blp + eo);
        }
        #pragma unroll
        for (int mt = 0; mt < 4; ++mt) {
            bf16x8 ah = ldA(Ahi, mt, kk, lane);
            bf16x8 al = ldA(Alo, mt, kk, lane);
            #pragma unroll
            for (int j = 0; j < 4; ++j) {
                acc[mt][j] = mfma16(ah, Bh[j], acc[mt][j]);
                acc[mt][j] = mfma16(ah, Bl[j], acc[mt][j]);
                acc[mt][j] = mfma16(al, Bh[j], acc[mt][j]);
            }
        }
    }
    const int mrow = (lane >> 4) * 4;
    #pragma unroll
    for (int mt = 0; mt < 4; ++mt) {
        #pragma unroll
        for (int reg = 0; reg < 4; ++reg) {
            int gr = row0 + mt * 16 + mrow + reg;       // = b*16384 + c*128 + s
            int b = gr >> 14, c = (gr >> 7) & 127, s = gr & 127;
            size_t rb = (size_t)((b * 128 + s) * 8) * 2048 + c * 16;
            #pragma unroll
            for (int j = 0; j < 4; ++j) {
                int n = nb + j * 16 + bcol;
                int h = n >> 4, p = n & 15;
                ob[rb + (size_t)h * 2048 + p] = acc[mt][j][reg];
            }
        }
    }
}

// ---------------------------------------------------------------------------
// Q projection (per-joint weights), split-bf16 MFMA. grid = (16, C).
// ---------------------------------------------------------------------------
__global__ __launch_bounds__(256) void q_mfma(
    const float* __restrict__ x,
    const ushort* __restrict__ wqhi, const ushort* __restrict__ wqlo,
    float* __restrict__ qb)
{
    __shared__ __align__(16) ushort Ahi[64 * 128];
    __shared__ __align__(16) ushort Alo[64 * 128];
    const int tid  = threadIdx.x;
    const int c    = blockIdx.y;
    const int row0 = blockIdx.x * 64;       // (b*S+s) space
    const int b0 = row0 >> 7, s0 = row0 & 127;
    stageA_f32(x + ((size_t)(b0 * 128 + c) * 128 + s0) * 128, Ahi, Alo, tid);
    __syncthreads();

    const int lane = tid & 63;
    const int w    = tid >> 6;
    const int bcol = lane & 15;
    const int bkg  = (lane >> 4) * 8;

    f32x4 zed; zed[0]=0.f; zed[1]=0.f; zed[2]=0.f; zed[3]=0.f;
    f32x4 acc[4][2];
    #pragma unroll
    for (int i = 0; i < 4; ++i) { acc[i][0] = zed; acc[i][1] = zed; }

    #pragma unroll
    for (int kk = 0; kk < 4; ++kk) {
        bf16x8 Bh[2], Bl[2];
        #pragma unroll
        for (int j = 0; j < 2; ++j) {
            int n = w * 32 + j * 16 + bcol;
            int h = n >> 4, p = n & 15;
            size_t eo = ((size_t)(h * 2048 + c * 16 + p)) * 128 + kk * 32 + bkg;
            Bh[j] = *(const bf16x8*)(wqhi + eo);
            Bl[j] = *(const bf16x8*)(wqlo + eo);
        }
        #pragma unroll
        for (int mt = 0; mt < 4; ++mt) {
            bf16x8 ah = ldA(Ahi, mt, kk, lane);
            bf16x8 al = ldA(Alo, mt, kk, lane);
            #pragma unroll
            for (int j = 0; j < 2; ++j) {
                acc[mt][j] = mfma16(ah, Bh[j], acc[mt][j]);
                acc[mt][j] = mfma16(ah, Bl[j], acc[mt][j]);
                acc[mt][j] = mfma16(al, Bh[j], acc[mt][j]);
            }
        }
    }
    const int mrow = (lane >> 4) * 4;
    #pragma unroll
    for (int mt = 0; mt < 4; ++mt) {
        #pragma unroll
        for (int reg = 0; reg < 4; ++reg) {
            int g = row0 + mt * 16 + mrow + reg;
            int b = g >> 7, s = g & 127;
            size_t rb = (size_t)((b * 128 + s) * 8) * 2048 + c * 16;
            #pragma unroll
            for (int j = 0; j < 2; ++j) {
                int n = w * 32 + j * 16 + bcol;
                int h = n >> 4, p = n & 15;
                qb[rb + (size_t)h * 2048 + p] = acc[mt][j][reg];
            }
        }
    }
}

// ---------------------------------------------------------------------------
// Output mixing, split-bf16 MFMA. A staged from o hi/lo planes (no convert).
// ---------------------------------------------------------------------------
__global__ __launch_bounds__(256) void out_mfma(
    const ushort* __restrict__ ohi, const ushort* __restrict__ olo,
    const ushort* __restrict__ wohi, const ushort* __restrict__ wolo,
    float* __restrict__ out)
{
    __shared__ __align__(16) ushort Ahi[64 * 128];
    __shared__ __align__(16) ushort Alo[64 * 128];
    const int tid  = threadIdx.x;
    const int c    = blockIdx.y;
    const int row0 = blockIdx.x * 64;
    const int b0 = row0 >> 7, s0 = row0 & 127;
    const size_t gbase = ((size_t)(b0 * 128 + c) * 128 + s0) * 128;
    stageA_bf16(ohi + gbase, olo + gbase, Ahi, Alo, tid);
    __syncthreads();

    const int lane = tid & 63;
    const int w    = tid >> 6;
    const int bcol = lane & 15;
    const int bkg  = (lane >> 4) * 8;

    f32x4 zed; zed[0]=0.f; zed[1]=0.f; zed[2]=0.f; zed[3]=0.f;
    f32x4 acc[4][2];
    #pragma unroll
    for (int i = 0; i < 4; ++i) { acc[i][0] = zed; acc[i][1] = zed; }

    #pragma unroll
    for (int kk = 0; kk < 4; ++kk) {
        bf16x8 Bh[2], Bl[2];
        #pragma unroll
        for (int j = 0; j < 2; ++j) {
            int f = w * 32 + j * 16 + bcol;
            size_t eo = ((size_t)(c * 128 + f)) * 128 + kk * 32 + bkg;
            Bh[j] = *(const bf16x8*)(wohi + eo);
            Bl[j] = *(const bf16x8*)(wolo + eo);
        }
        #pragma unroll
        for (int mt = 0; mt < 4; ++mt) {
            bf16x8 ah = ldA(Ahi, mt, kk, lane);
            bf16x8 al = ldA(Alo, mt, kk, lane);
            #pragma unroll
            for (int j = 0; j < 2; ++j) {
                acc[mt][j] = mfma16(ah, Bh[j], acc[mt][j]);
                acc[mt][j] = mfma16(ah, Bl[j], acc[mt][j]);
                acc[mt][j] = mfma16(al, Bh[j], acc[mt][j]);
            }
        }
    }
    const int mrow = (lane >> 4) * 4;
    #pragma unroll
    for (int mt = 0; mt < 4; ++mt) {
        #pragma unroll
        for (int reg = 0; reg < 4; ++reg) {
            int m = mt * 16 + mrow + reg;
            #pragma unroll
            for (int j = 0; j < 2; ++j) {
                int f = w * 32 + j * 16 + bcol;
                out[gbase + (size_t)m * 128 + f] = acc[mt][j][reg];
            }
        }
    }
}

// ---------------------------------------------------------------------------
// Attention (f32, unchanged math) — writes o as bf16 hi/lo planes.
// ---------------------------------------------------------------------------
__global__ __launch_bounds__(256) void attn_kernel(
    const float* __restrict__ qb, const float* __restrict__ kb,
    const float* __restrict__ vb, ushort* __restrict__ ohi, ushort* __restrict__ olo)
{
    __shared__ float qs[128][17];
    __shared__ float ks[128][17];
    __shared__ float vs[128][20];
    __shared__ float As[64][133];
    const int tid = threadIdx.x;
    const int idx = blockIdx.x;                 // = (b*S+s)*H + h
    const size_t base = (size_t)idx * (NC * NP);
    #pragma unroll
    for (int i = 0; i < 2; ++i) {
        int f4 = i * 256 + tid;
        int d = f4 >> 2, pp = (f4 & 3) * 4;
        float4 tq = *(const float4*)(qb + base + f4 * 4);
        qs[d][pp] = tq.x; qs[d][pp+1] = tq.y; qs[d][pp+2] = tq.z; qs[d][pp+3] = tq.w;
        float4 tk = *(const float4*)(kb + base + f4 * 4);
        ks[d][pp] = tk.x; ks[d][pp+1] = tk.y; ks[d][pp+2] = tk.z; ks[d][pp+3] = tk.w;
        float4 tv = *(const float4*)(vb + base + f4 * 4);
        vs[d][pp] = tv.x; vs[d][pp+1] = tv.y; vs[d][pp+2] = tv.z; vs[d][pp+3] = tv.w;
    }
    __syncthreads();
    const int ty = tid >> 4, tx = tid & 15;
    const int h  = idx & (NH - 1);
    const int bs = idx >> 3;
    const int b  = bs >> 7, s = bs & (NS - 1);

    for (int half = 0; half < 2; ++half) {
        float sc[4][8];
        #pragma unroll
        for (int r = 0; r < 4; ++r)
            #pragma unroll
            for (int k = 0; k < 8; ++k) sc[r][k] = 0.f;
        for (int pp = 0; pp < 16; ++pp) {
            float qv[4], kv[8];
            #pragma unroll
            for (int r = 0; r < 4; ++r) qv[r] = qs[half * 64 + ty + 16 * r][pp];
            #pragma unroll
            for (int k = 0; k < 8; ++k) kv[k] = ks[tx + 16 * k][pp];
            #pragma unroll
            for (int r = 0; r < 4; ++r)
                #pragma unroll
                for (int k = 0; k < 8; ++k) sc[r][k] += qv[r] * kv[k];
        }
        #pragma unroll
        for (int r = 0; r < 4; ++r) {
            float m = -1e30f;
            #pragma unroll
            for (int k = 0; k < 8; ++k) { sc[r][k] *= 0.25f; m = fmaxf(m, sc[r][k]); }
            #pragma unroll
            for (int o = 1; o < 16; o <<= 1) m = fmaxf(m, __shfl_xor(m, o));
            float sum = 0.f;
            #pragma unroll
            for (int k = 0; k < 8; ++k) { sc[r][k] = __expf(sc[r][k] - m); sum += sc[r][k]; }
            #pragma unroll
            for (int o = 1; o < 16; o <<= 1) sum += __shfl_xor(sum, o);
            float inv = 1.0f / sum;
            #pragma unroll
            for (int k = 0; k < 8; ++k) As[ty + 16 * r][tx + 16 * k] = sc[r][k] * inv;
        }
        __syncthreads();
        const int p4 = (tid & 3) * 4;
        const int cr = tid >> 2;
        float o0[4] = {0.f, 0.f, 0.f, 0.f};
        for (int d = 0; d < 128; ++d) {
            float4 vv = *(const float4*)(&vs[d][p4]);
            float a0 = As[cr][d];
            o0[0] += a0 * vv.x; o0[1] += a0 * vv.y; o0[2] += a0 * vv.z; o0[3] += a0 * vv.w;
        }
        int cc = half * 64 + cr;
        size_t obase = ((size_t)(b * NC + cc) * NS + s) * NE + h * NP + p4;
        uint hA, lA, hB, lB;
        cvt2(o0[0], o0[1], hA, lA);
        cvt2(o0[2], o0[3], hB, lB);
        *(uint2*)((char*)ohi + obase * 2) = make_uint2(hA, hB);
        *(uint2*)((char*)olo + obase * 2) = make_uint2(lA, lB);
        __syncthreads();
    }
}

// Sentinel: unambiguous signal that ws_size was too small.
__global__ void sentinel_kernel(float* out, int n) {
    int i = blockIdx.x * 256 + threadIdx.x;
    if (i < n) out[i] = 1.0e6f;
}

extern "C" void kernel_launch(void* const* d_in, const int* in_sizes, int n_in,
                              void* d_out, int out_size, void* d_ws, size_t ws_size,
                              hipStream_t stream)
{
    const float* x  = (const float*)d_in[0];
    const float* Wq = (const float*)d_in[1];
    const float* Wk = (const float*)d_in[2];
    const float* Wv = (const float*)d_in[3];
    const float* Wo = (const float*)d_in[4];
    float* out = (float*)d_out;
    float* ws  = (float*)d_ws;

    const size_t CH = (size_t)CHUNK;
    // Persistent-phase layout: exactly 256 MiB.
    float*  qbuf = ws;                        // 64 MiB, dead after attn
    float*  kbuf = ws + CH;                   // 64 MiB
    float*  vbuf = ws + 2 * CH;               // 64 MiB
    ushort* ohi  = (ushort*)(ws + 3 * CH);    // 32 MiB, written by attn
    ushort* olo  = ohi + CH;                  // 32 MiB
    // Phase-1 weights alias the o region (dead until attn runs):
    ushort* wqhi = ohi;                       // 4 MiB
    ushort* wqlo = wqhi + WQ_ELEMS;           // 4 MiB
    ushort* wkhi = wqlo + WQ_ELEMS;
    ushort* wklo = wkhi + WKV_ELEMS;
    ushort* wvhi = wklo + WKV_ELEMS;
    ushort* wvlo = wvhi + WKV_ELEMS;
    // Phase-2 weights alias the q region (dead after attn); packed post-attn:
    ushort* wohi = (ushort*)qbuf;             // 4 MiB
    ushort* wolo = wohi + WO_ELEMS;           // 4 MiB

    const size_t need = 4 * CH * sizeof(float);   // 268,435,456 B = 256 MiB
    if (ws_size < need) {
        sentinel_kernel<<<(out_size + 255) / 256, 256, 0, stream>>>(out, out_size);
        return;
    }

    pack_linear<<<WQ_ELEMS / 4 / 256, 256, 0, stream>>>(Wq, wqhi, wqlo, WQ_ELEMS / 4);
    pack_kvw<<<WKV_ELEMS / 256, 256, 0, stream>>>(Wk, wkhi, wklo);
    pack_kvw<<<WKV_ELEMS / 256, 256, 0, stream>>>(Wv, wvhi, wvlo);

    kv_mfma<<<NROWS / 64, 256, 0, stream>>>(x, wkhi, wklo, wvhi, wvlo, kbuf, vbuf);
    q_mfma<<<dim3(BSROWS / 64, NC), 256, 0, stream>>>(x, wqhi, wqlo, qbuf);
    attn_kernel<<<BSROWS * NH, 256, 0, stream>>>(qbuf, kbuf, vbuf, ohi, olo);

    pack_wo<<<dim3(4, NC), 256, 0, stream>>>(Wo, wohi, wolo);   // into dead q region
    out_mfma<<<dim3(BSROWS / 64, NC), 256, 0, stream>>>(ohi, olo, wohi, wolo, out);
}

// Round 4
// 396.821 us; speedup vs baseline: 1.6353x; 1.2826x over previous
//
#include <hip/hip_runtime.h>

typedef unsigned int uint;
typedef unsigned short ushort;

// Problem constants
#define NB 8
#define NC 128
#define NS 128
#define NE 128
#define NH 8
#define NP 16
#define BSROWS (NB*NS)            // 1024
#define NROWS  (NB*NC*NS)         // 131072
#define CHUNK  (BSROWS*NH*NC*NP)  // 16,777,216 elems per q/k/v/o buffer
#define WQ_ELEMS 2097152          // 8*128*16*128
#define WO_ELEMS 2097152          // 128*128*128
#define WKV_ELEMS 16384           // 8*128*16

using bf16x8 = __attribute__((ext_vector_type(8))) short;
using f32x4  = __attribute__((ext_vector_type(4))) float;
using f32x16 = __attribute__((ext_vector_type(16))) float;

__device__ __forceinline__ f32x4 mfma16(bf16x8 a, bf16x8 b, f32x4 c) {
    return __builtin_amdgcn_mfma_f32_16x16x32_bf16(a, b, c, 0, 0, 0);
}
__device__ __forceinline__ f32x16 mfma32(bf16x8 a, bf16x8 b, f32x16 c) {
    return __builtin_amdgcn_mfma_f32_32x32x16_bf16(a, b, c, 0, 0, 0);
}

// f32 -> (bf16 hi, bf16 lo) split: hi = RNE(f), lo = trunc(f - hi).
__device__ __forceinline__ void cvt_hilo(float f, uint& h, uint& l) {
    uint u  = __float_as_uint(f);
    uint hh = (u + 0x7FFFu + ((u >> 16) & 1u)) >> 16;   // RNE to bf16
    float r = f - __uint_as_float(hh << 16);            // exact
    h = hh;
    l = __float_as_uint(r) >> 16;                       // truncate (fine for lo)
}
__device__ __forceinline__ void cvt2(float f0, float f1, uint& hp, uint& lp) {
    uint h0, l0, h1, l1;
    cvt_hilo(f0, h0, l0); cvt_hilo(f1, h1, l1);
    hp = h0 | (h1 << 16); lp = l0 | (l1 << 16);
}
__device__ __forceinline__ uint rnepack(float a, float b) {
    uint ua = __float_as_uint(a), ub = __float_as_uint(b);
    uint ha = (ua + 0x7FFFu + ((ua >> 16) & 1u)) >> 16;
    uint hb = (ub + 0x7FFFu + ((ub >> 16) & 1u)) >> 16;
    return ha | (hb << 16);
}
__device__ __forceinline__ void cvt8(float4 a, float4 b, bf16x8& h, bf16x8& l) {
    float v[8] = {a.x, a.y, a.z, a.w, b.x, b.y, b.z, b.w};
    #pragma unroll
    for (int i = 0; i < 8; ++i) {
        uint hh, ll; cvt_hilo(v[i], hh, ll);
        h[i] = (short)hh; l[i] = (short)ll;
    }
}

// ---------------------------------------------------------------------------
// LDS A-tile: 64 rows x 128 k, bf16 hi/lo planes, XOR-swizzled 16B chunks
// ---------------------------------------------------------------------------
__device__ __forceinline__ void stageA_f32(const float* __restrict__ src,
                                           ushort* Ahi, ushort* Alo, int tid) {
    #pragma unroll
    for (int i = 0; i < 4; ++i) {
        int f8  = i * 256 + tid;      // 8-elem chunk id, 1024 total
        int row = f8 >> 4;
        int kc  = f8 & 15;
        const float* rp = src + row * 128 + kc * 8;
        float4 v0 = *(const float4*)rp;
        float4 v1 = *(const float4*)(rp + 4);
        uint h0,l0,h1,l1,h2,l2,h3,l3;
        cvt2(v0.x, v0.y, h0, l0); cvt2(v0.z, v0.w, h1, l1);
        cvt2(v1.x, v1.y, h2, l2); cvt2(v1.z, v1.w, h3, l3);
        int off = row * 256 + ((kc * 16) ^ ((row & 7) << 4));
        *(uint4*)((char*)Ahi + off) = make_uint4(h0, h1, h2, h3);
        *(uint4*)((char*)Alo + off) = make_uint4(l0, l1, l2, l3);
    }
}

__device__ __forceinline__ void stageA_bf16(const ushort* __restrict__ hsrc,
                                            const ushort* __restrict__ lsrc,
                                            ushort* Ahi, ushort* Alo, int tid) {
    #pragma unroll
    for (int i = 0; i < 4; ++i) {
        int f8  = i * 256 + tid;
        int row = f8 >> 4;
        int kc  = f8 & 15;
        uint4 hv = *(const uint4*)((const char*)hsrc + (size_t)(row * 128 + kc * 8) * 2);
        uint4 lv = *(const uint4*)((const char*)lsrc + (size_t)(row * 128 + kc * 8) * 2);
        int off = row * 256 + ((kc * 16) ^ ((row & 7) << 4));
        *(uint4*)((char*)Ahi + off) = hv;
        *(uint4*)((char*)Alo + off) = lv;
    }
}

// A-fragment read: lane holds A[row = mt*16 + (l&15)][k = kk*32 + (l>>4)*8 + 0..7]
__device__ __forceinline__ bf16x8 ldA(const ushort* A, int mt, int kk, int lane) {
    int row = mt * 16 + (lane & 15);
    int kb  = kk * 64 + ((lane >> 4) << 4);   // byte offset within row
    int off = row * 256 + (kb ^ ((row & 7) << 4));
    return *(const bf16x8*)((const char*)A + off);
}

// ---------------------------------------------------------------------------
// Weight packing (re-run every launch; buffers alias dead ws phases)
// ---------------------------------------------------------------------------
__global__ __launch_bounds__(256) void pack_linear(
    const float* __restrict__ src, ushort* __restrict__ dh, ushort* __restrict__ dl, int n4)
{
    int i = blockIdx.x * 256 + threadIdx.x;
    if (i >= n4) return;
    float4 v = ((const float4*)src)[i];
    uint h0,l0,h1,l1;
    cvt2(v.x, v.y, h0, l0); cvt2(v.z, v.w, h1, l1);
    ((uint2*)dh)[i] = make_uint2(h0, h1);
    ((uint2*)dl)[i] = make_uint2(l0, l1);
}

// Wk/Wv [h,e,p] -> [h*16+p][e]
__global__ __launch_bounds__(256) void pack_kvw(
    const float* __restrict__ src, ushort* __restrict__ dh, ushort* __restrict__ dl)
{
    int idx = blockIdx.x * 256 + threadIdx.x;    // 16384
    int hp = idx >> 7, e = idx & 127;
    int h = hp >> 4, p = hp & 15;
    float v = src[(h * 128 + e) * 16 + p];
    uint hh, ll; cvt_hilo(v, hh, ll);
    dh[idx] = (ushort)hh; dl[idx] = (ushort)ll;
}

// Wo [c,e,f] -> [c*128+f][e] via LDS transpose
__global__ __launch_bounds__(256) void pack_wo(
    const float* __restrict__ Wo, ushort* __restrict__ dh, ushort* __restrict__ dl)
{
    __shared__ float t[32][129];
    const int tid = threadIdx.x;
    const int c = blockIdx.y, ec = blockIdx.x * 32;
    #pragma unroll
    for (int i = 0; i < 16; ++i) {
        int idx = i * 256 + tid;                 // 4096 = 32*128
        int e = idx >> 7, f = idx & 127;
        t[e][f] = Wo[((size_t)(c * 128) + ec + e) * 128 + f];
    }
    __syncthreads();
    #pragma unroll
    for (int i = 0; i < 8; ++i) {
        int o2 = i * 256 + tid;                  // 2048 pairs
        int f = o2 >> 4, e2 = o2 & 15;
        uint hh, ll;
        cvt2(t[2 * e2][f], t[2 * e2 + 1][f], hh, ll);
        size_t oo = ((size_t)(c * 128 + f)) * 128 + ec + 2 * e2;   // even
        *(uint*)((char*)dh + oo * 2) = hh;
        *(uint*)((char*)dl + oo * 2) = ll;
    }
}

// ---------------------------------------------------------------------------
// K/V projection, split-bf16 MFMA. (unchanged from R3)
// ---------------------------------------------------------------------------
__global__ __launch_bounds__(256) void kv_mfma(
    const float* __restrict__ x,
    const ushort* __restrict__ wkhi, const ushort* __restrict__ wklo,
    const ushort* __restrict__ wvhi, const ushort* __restrict__ wvlo,
    float* __restrict__ kb, float* __restrict__ vb)
{
    __shared__ __align__(16) ushort Ahi[64 * 128];
    __shared__ __align__(16) ushort Alo[64 * 128];
    const int tid  = threadIdx.x;
    const int row0 = blockIdx.x * 64;
    stageA_f32(x + (size_t)row0 * 128, Ahi, Alo, tid);
    __syncthreads();

    const int lane = tid & 63;
    const int w    = tid >> 6;
    const ushort* bhp = (w >> 1) ? wvhi : wkhi;
    const ushort* blp = (w >> 1) ? wvlo : wklo;
    float* ob = (w >> 1) ? vb : kb;
    const int nb   = (w & 1) * 64;
    const int bcol = lane & 15;
    const int bkg  = (lane >> 4) * 8;

    f32x4 zed; zed[0]=0.f; zed[1]=0.f; zed[2]=0.f; zed[3]=0.f;
    f32x4 acc[4][4];
    #pragma unroll
    for (int i = 0; i < 4; ++i)
        #pragma unroll
        for (int j = 0; j < 4; ++j) acc[i][j] = zed;

    #pragma unroll
    for (int kk = 0; kk < 4; ++kk) {
        bf16x8 Bh[4], Bl[4];
        #pragma unroll
        for (int j = 0; j < 4; ++j) {
            int n = nb + j * 16 + bcol;
            size_t eo = (size_t)n * 128 + kk * 32 + bkg;
            Bh[j] = *(const bf16x8*)(bhp + eo);
            Bl[j] = *(const bf16x8*)(blp + eo);
        }
        #pragma unroll
        for (int mt = 0; mt < 4; ++mt) {
            bf16x8 ah = ldA(Ahi, mt, kk, lane);
            bf16x8 al = ldA(Alo, mt, kk, lane);
            #pragma unroll
            for (int j = 0; j < 4; ++j) {
                acc[mt][j] = mfma16(ah, Bh[j], acc[mt][j]);
                acc[mt][j] = mfma16(ah, Bl[j], acc[mt][j]);
                acc[mt][j] = mfma16(al, Bh[j], acc[mt][j]);
            }
        }
    }
    const int mrow = (lane >> 4) * 4;
    #pragma unroll
    for (int mt = 0; mt < 4; ++mt) {
        #pragma unroll
        for (int reg = 0; reg < 4; ++reg) {
            int gr = row0 + mt * 16 + mrow + reg;       // = b*16384 + c*128 + s
            int b = gr >> 14, c = (gr >> 7) & 127, s = gr & 127;
            size_t rb = (size_t)((b * 128 + s) * 8) * 2048 + c * 16;
            #pragma unroll
            for (int j = 0; j < 4; ++j) {
                int n = nb + j * 16 + bcol;
                int h = n >> 4, p = n & 15;
                ob[rb + (size_t)h * 2048 + p] = acc[mt][j][reg];
            }
        }
    }
}

// ---------------------------------------------------------------------------
// Q projection (unchanged from R3)
// ---------------------------------------------------------------------------
__global__ __launch_bounds__(256) void q_mfma(
    const float* __restrict__ x,
    const ushort* __restrict__ wqhi, const ushort* __restrict__ wqlo,
    float* __restrict__ qb)
{
    __shared__ __align__(16) ushort Ahi[64 * 128];
    __shared__ __align__(16) ushort Alo[64 * 128];
    const int tid  = threadIdx.x;
    const int c    = blockIdx.y;
    const int row0 = blockIdx.x * 64;       // (b*S+s) space
    const int b0 = row0 >> 7, s0 = row0 & 127;
    stageA_f32(x + ((size_t)(b0 * 128 + c) * 128 + s0) * 128, Ahi, Alo, tid);
    __syncthreads();

    const int lane = tid & 63;
    const int w    = tid >> 6;
    const int bcol = lane & 15;
    const int bkg  = (lane >> 4) * 8;

    f32x4 zed; zed[0]=0.f; zed[1]=0.f; zed[2]=0.f; zed[3]=0.f;
    f32x4 acc[4][2];
    #pragma unroll
    for (int i = 0; i < 4; ++i) { acc[i][0] = zed; acc[i][1] = zed; }

    #pragma unroll
    for (int kk = 0; kk < 4; ++kk) {
        bf16x8 Bh[2], Bl[2];
        #pragma unroll
        for (int j = 0; j < 2; ++j) {
            int n = w * 32 + j * 16 + bcol;
            int h = n >> 4, p = n & 15;
            size_t eo = ((size_t)(h * 2048 + c * 16 + p)) * 128 + kk * 32 + bkg;
            Bh[j] = *(const bf16x8*)(wqhi + eo);
            Bl[j] = *(const bf16x8*)(wqlo + eo);
        }
        #pragma unroll
        for (int mt = 0; mt < 4; ++mt) {
            bf16x8 ah = ldA(Ahi, mt, kk, lane);
            bf16x8 al = ldA(Alo, mt, kk, lane);
            #pragma unroll
            for (int j = 0; j < 2; ++j) {
                acc[mt][j] = mfma16(ah, Bh[j], acc[mt][j]);
                acc[mt][j] = mfma16(ah, Bl[j], acc[mt][j]);
                acc[mt][j] = mfma16(al, Bh[j], acc[mt][j]);
            }
        }
    }
    const int mrow = (lane >> 4) * 4;
    #pragma unroll
    for (int mt = 0; mt < 4; ++mt) {
        #pragma unroll
        for (int reg = 0; reg < 4; ++reg) {
            int g = row0 + mt * 16 + mrow + reg;
            int b = g >> 7, s = g & 127;
            size_t rb = (size_t)((b * 128 + s) * 8) * 2048 + c * 16;
            #pragma unroll
            for (int j = 0; j < 2; ++j) {
                int n = w * 32 + j * 16 + bcol;
                int h = n >> 4, p = n & 15;
                qb[rb + (size_t)h * 2048 + p] = acc[mt][j][reg];
            }
        }
    }
}

// ---------------------------------------------------------------------------
// Output mixing (unchanged from R3)
// ---------------------------------------------------------------------------
__global__ __launch_bounds__(256) void out_mfma(
    const ushort* __restrict__ ohi, const ushort* __restrict__ olo,
    const ushort* __restrict__ wohi, const ushort* __restrict__ wolo,
    float* __restrict__ out)
{
    __shared__ __align__(16) ushort Ahi[64 * 128];
    __shared__ __align__(16) ushort Alo[64 * 128];
    const int tid  = threadIdx.x;
    const int c    = blockIdx.y;
    const int row0 = blockIdx.x * 64;
    const int b0 = row0 >> 7, s0 = row0 & 127;
    const size_t gbase = ((size_t)(b0 * 128 + c) * 128 + s0) * 128;
    stageA_bf16(ohi + gbase, olo + gbase, Ahi, Alo, tid);
    __syncthreads();

    const int lane = tid & 63;
    const int w    = tid >> 6;
    const int bcol = lane & 15;
    const int bkg  = (lane >> 4) * 8;

    f32x4 zed; zed[0]=0.f; zed[1]=0.f; zed[2]=0.f; zed[3]=0.f;
    f32x4 acc[4][2];
    #pragma unroll
    for (int i = 0; i < 4; ++i) { acc[i][0] = zed; acc[i][1] = zed; }

    #pragma unroll
    for (int kk = 0; kk < 4; ++kk) {
        bf16x8 Bh[2], Bl[2];
        #pragma unroll
        for (int j = 0; j < 2; ++j) {
            int f = w * 32 + j * 16 + bcol;
            size_t eo = ((size_t)(c * 128 + f)) * 128 + kk * 32 + bkg;
            Bh[j] = *(const bf16x8*)(wohi + eo);
            Bl[j] = *(const bf16x8*)(wolo + eo);
        }
        #pragma unroll
        for (int mt = 0; mt < 4; ++mt) {
            bf16x8 ah = ldA(Ahi, mt, kk, lane);
            bf16x8 al = ldA(Alo, mt, kk, lane);
            #pragma unroll
            for (int j = 0; j < 2; ++j) {
                acc[mt][j] = mfma16(ah, Bh[j], acc[mt][j]);
                acc[mt][j] = mfma16(ah, Bl[j], acc[mt][j]);
                acc[mt][j] = mfma16(al, Bh[j], acc[mt][j]);
            }
        }
    }
    const int mrow = (lane >> 4) * 4;
    #pragma unroll
    for (int mt = 0; mt < 4; ++mt) {
        #pragma unroll
        for (int reg = 0; reg < 4; ++reg) {
            int m = mt * 16 + mrow + reg;
            #pragma unroll
            for (int j = 0; j < 2; ++j) {
                int f = w * 32 + j * 16 + bcol;
                out[gbase + (size_t)m * 128 + f] = acc[mt][j][reg];
            }
        }
    }
}

// ---------------------------------------------------------------------------
// Attention, MFMA version. Block = (b,s,h), 4 waves.
// Scores: S^T = mfma_32x32x16(A=K, B=Q) -> lane's col = c, softmax is in-lane
// over 64 regs + one shfl_xor(32). P (bf16 hi) packed to LDS via b64 writes.
// PV: mfma_16x16x32(A=P, B=V^T hi/lo from LDS).
// ---------------------------------------------------------------------------
__global__ __launch_bounds__(256) void attn_mfma(
    const float* __restrict__ qb, const float* __restrict__ kb,
    const float* __restrict__ vb, ushort* __restrict__ ohi, ushort* __restrict__ olo)
{
    __shared__ __align__(16) ushort VTh[16][136];   // V^T hi, stride 136: 2-way free b128 reads
    __shared__ __align__(16) ushort VTl[16][136];
    __shared__ __align__(16) ushort Pw[4][32][136]; // per-wave P rows (bf16 hi)
    const int tid  = threadIdx.x;
    const int idx  = blockIdx.x;                    // = (b*S+s)*H + h
    const size_t base = (size_t)idx * 2048;

    // ---- stage V transposed into LDS (hi/lo), rotated j-order to dodge
    //      same-word write collisions ----
    {
        int d = tid >> 1, p0 = (tid & 1) * 8;
        const float* vp = vb + base + d * 16 + p0;
        float4 va = *(const float4*)vp;
        float4 vb4 = *(const float4*)(vp + 4);
        float vals[8] = {va.x, va.y, va.z, va.w, vb4.x, vb4.y, vb4.z, vb4.w};
        int rot = (d & 1) * 4;
        #pragma unroll
        for (int jj = 0; jj < 8; ++jj) {
            int j = (jj + rot) & 7;
            uint h, l; cvt_hilo(vals[j], h, l);
            VTh[p0 + j][d] = (ushort)h;
            VTl[p0 + j][d] = (ushort)l;
        }
    }

    // ---- Q (B-frag) / K (A-frags) register loads with hi/lo split ----
    const int lane = tid & 63;
    const int w    = tid >> 6;        // wave = c-tile
    const int cg   = lane & 31;
    const int ph   = (lane >> 5) * 8; // p-half
    bf16x8 Qh, Ql, Kh[4], Kl[4];
    {
        const float* qp = qb + base + (w * 32 + cg) * 16 + ph;
        cvt8(*(const float4*)qp, *(const float4*)(qp + 4), Qh, Ql);
        #pragma unroll
        for (int dt = 0; dt < 4; ++dt) {
            const float* kp = kb + base + (dt * 32 + cg) * 16 + ph;
            cvt8(*(const float4*)kp, *(const float4*)(kp + 4), Kh[dt], Kl[dt]);
        }
    }
    __syncthreads();

    // ---- scores S^T: acc[dt] covers d = 32dt+row, c = 32w + cg ----
    f32x16 S[4];
    #pragma unroll
    for (int dt = 0; dt < 4; ++dt)
        #pragma unroll
        for (int r = 0; r < 16; ++r) S[dt][r] = 0.f;
    #pragma unroll
    for (int dt = 0; dt < 4; ++dt) {
        S[dt] = mfma32(Kh[dt], Qh, S[dt]);
        S[dt] = mfma32(Kh[dt], Ql, S[dt]);
        S[dt] = mfma32(Kl[dt], Qh, S[dt]);
    }

    // ---- softmax over d (64 in-lane values + lane-pair exchange) ----
    float m = -1e30f;
    #pragma unroll
    for (int dt = 0; dt < 4; ++dt)
        #pragma unroll
        for (int r = 0; r < 16; ++r) { S[dt][r] *= 0.25f; m = fmaxf(m, S[dt][r]); }
    m = fmaxf(m, __shfl_xor(m, 32));
    float sum = 0.f;
    #pragma unroll
    for (int dt = 0; dt < 4; ++dt)
        #pragma unroll
        for (int r = 0; r < 16; ++r) { S[dt][r] = __expf(S[dt][r] - m); sum += S[dt][r]; }
    sum += __shfl_xor(sum, 32);
    const float inv = 1.0f / sum;

    // ---- pack P rows to LDS: 4 consecutive d per b64 write ----
    const int hi4 = (lane >> 5) * 4;
    #pragma unroll
    for (int dt = 0; dt < 4; ++dt) {
        #pragma unroll
        for (int q = 0; q < 4; ++q) {
            float p0 = S[dt][4*q+0] * inv, p1 = S[dt][4*q+1] * inv;
            float p2 = S[dt][4*q+2] * inv, p3 = S[dt][4*q+3] * inv;
            uint w0 = rnepack(p0, p1), w1 = rnepack(p2, p3);
            *(uint2*)&Pw[w][cg][dt * 32 + q * 8 + hi4] = make_uint2(w0, w1);
        }
    }
    __syncthreads();   // orders Pw writes (lgkm drain) + VT visibility

    // ---- PV: O[c 32][p 16] per wave ----
    f32x4 O[2];
    #pragma unroll
    for (int mt = 0; mt < 2; ++mt) { O[mt][0]=0.f; O[mt][1]=0.f; O[mt][2]=0.f; O[mt][3]=0.f; }
    const int pcol = lane & 15;
    const int dg   = (lane >> 4) * 8;
    #pragma unroll
    for (int ks = 0; ks < 4; ++ks) {
        bf16x8 Bh = *(const bf16x8*)&VTh[pcol][ks * 32 + dg];
        bf16x8 Bl = *(const bf16x8*)&VTl[pcol][ks * 32 + dg];
        #pragma unroll
        for (int mt = 0; mt < 2; ++mt) {
            bf16x8 A = *(const bf16x8*)&Pw[w][mt * 16 + pcol][ks * 32 + dg];
            O[mt] = mfma16(A, Bh, O[mt]);
            O[mt] = mfma16(A, Bl, O[mt]);
        }
    }

    // ---- epilogue: o -> [B,C,S,E] bf16 hi/lo planes ----
    const int h  = idx & 7;
    const int bs = idx >> 3;
    const int b  = bs >> 7, s = bs & 127;
    const int rg = (lane >> 4) * 4;
    #pragma unroll
    for (int mt = 0; mt < 2; ++mt) {
        #pragma unroll
        for (int reg = 0; reg < 4; ++reg) {
            int c = w * 32 + mt * 16 + rg + reg;
            uint hh, ll; cvt_hilo(O[mt][reg], hh, ll);
            size_t ob = ((size_t)(b * 128 + c) * 128 + s) * 128 + h * 16 + pcol;
            ohi[ob] = (ushort)hh;
            olo[ob] = (ushort)ll;
        }
    }
}

// Sentinel: unambiguous signal that ws_size was too small.
__global__ void sentinel_kernel(float* out, int n) {
    int i = blockIdx.x * 256 + threadIdx.x;
    if (i < n) out[i] = 1.0e6f;
}

extern "C" void kernel_launch(void* const* d_in, const int* in_sizes, int n_in,
                              void* d_out, int out_size, void* d_ws, size_t ws_size,
                              hipStream_t stream)
{
    const float* x  = (const float*)d_in[0];
    const float* Wq = (const float*)d_in[1];
    const float* Wk = (const float*)d_in[2];
    const float* Wv = (const float*)d_in[3];
    const float* Wo = (const float*)d_in[4];
    float* out = (float*)d_out;
    float* ws  = (float*)d_ws;

    const size_t CH = (size_t)CHUNK;
    // Persistent-phase layout: exactly 256 MiB.
    float*  qbuf = ws;                        // 64 MiB, dead after attn
    float*  kbuf = ws + CH;                   // 64 MiB
    float*  vbuf = ws + 2 * CH;               // 64 MiB
    ushort* ohi  = (ushort*)(ws + 3 * CH);    // 32 MiB, written by attn
    ushort* olo  = ohi + CH;                  // 32 MiB
    // Phase-1 weights alias the o region (dead until attn runs):
    ushort* wqhi = ohi;
    ushort* wqlo = wqhi + WQ_ELEMS;
    ushort* wkhi = wqlo + WQ_ELEMS;
    ushort* wklo = wkhi + WKV_ELEMS;
    ushort* wvhi = wklo + WKV_ELEMS;
    ushort* wvlo = wvhi + WKV_ELEMS;
    // Phase-2 weights alias the q region (dead after attn); packed post-attn:
    ushort* wohi = (ushort*)qbuf;
    ushort* wolo = wohi + WO_ELEMS;

    const size_t need = 4 * CH * sizeof(float);   // 268,435,456 B = 256 MiB
    if (ws_size < need) {
        sentinel_kernel<<<(out_size + 255) / 256, 256, 0, stream>>>(out, out_size);
        return;
    }

    pack_linear<<<WQ_ELEMS / 4 / 256, 256, 0, stream>>>(Wq, wqhi, wqlo, WQ_ELEMS / 4);
    pack_kvw<<<WKV_ELEMS / 256, 256, 0, stream>>>(Wk, wkhi, wklo);
    pack_kvw<<<WKV_ELEMS / 256, 256, 0, stream>>>(Wv, wvhi, wvlo);

    kv_mfma<<<NROWS / 64, 256, 0, stream>>>(x, wkhi, wklo, wvhi, wvlo, kbuf, vbuf);
    q_mfma<<<dim3(BSROWS / 64, NC), 256, 0, stream>>>(x, wqhi, wqlo, qbuf);
    attn_mfma<<<BSROWS * NH, 256, 0, stream>>>(qbuf, kbuf, vbuf, ohi, olo);

    pack_wo<<<dim3(4, NC), 256, 0, stream>>>(Wo, wohi, wolo);   // into dead q region
    out_mfma<<<dim3(BSROWS / 64, NC), 256, 0, stream>>>(ohi, olo, wohi, wolo, out);
}

// Round 5
// 302.771 us; speedup vs baseline: 2.1432x; 1.3106x over previous
//
#include <hip/hip_runtime.h>

typedef unsigned int uint;
typedef unsigned short ushort;

// Problem constants
#define NB 8
#define NC 128
#define NS 128
#define NE 128
#define NH 8
#define NP 16
#define BSROWS (NB*NS)            // 1024
#define NROWS  (NB*NC*NS)         // 131072
#define CHUNK  (BSROWS*NH*NC*NP)  // 16,777,216 elems per q/k/v/o buffer
#define WQ_ELEMS 2097152          // 8*128*16*128
#define WO_ELEMS 2097152          // 128*128*128
#define WKV_ELEMS 16384           // 8*128*16

using bf16x8 = __attribute__((ext_vector_type(8))) short;
using f32x4  = __attribute__((ext_vector_type(4))) float;
using f32x16 = __attribute__((ext_vector_type(16))) float;

__device__ __forceinline__ f32x4 mfma16(bf16x8 a, bf16x8 b, f32x4 c) {
    return __builtin_amdgcn_mfma_f32_16x16x32_bf16(a, b, c, 0, 0, 0);
}
__device__ __forceinline__ f32x16 mfma32(bf16x8 a, bf16x8 b, f32x16 c) {
    return __builtin_amdgcn_mfma_f32_32x32x16_bf16(a, b, c, 0, 0, 0);
}

// f32 -> bf16 RNE (bit math, proven in R3/R4)
__device__ __forceinline__ uint rne1(float f) {
    uint u = __float_as_uint(f);
    return (u + 0x7FFFu + ((u >> 16) & 1u)) >> 16;
}
__device__ __forceinline__ uint rnepack(float a, float b) {
    return rne1(a) | (rne1(b) << 16);
}
// f32 -> (bf16 hi, bf16 lo) split (only where precision matters: o, Wo)
__device__ __forceinline__ void cvt_hilo(float f, uint& h, uint& l) {
    uint hh = rne1(f);
    float r = f - __uint_as_float(hh << 16);            // exact
    h = hh;
    l = __float_as_uint(r) >> 16;
}
__device__ __forceinline__ void cvt2(float f0, float f1, uint& hp, uint& lp) {
    uint h0, l0, h1, l1;
    cvt_hilo(f0, h0, l0); cvt_hilo(f1, h1, l1);
    hp = h0 | (h1 << 16); lp = l0 | (l1 << 16);
}

// ---------------------------------------------------------------------------
// LDS A-tile staging: 64 rows x 128 k, XOR-swizzled 16B chunks
// ---------------------------------------------------------------------------
__device__ __forceinline__ void stageA_hi(const float* __restrict__ src,
                                          ushort* A, int tid) {
    #pragma unroll
    for (int i = 0; i < 4; ++i) {
        int f8  = i * 256 + tid;      // 8-elem chunk id, 1024 total
        int row = f8 >> 4;
        int kc  = f8 & 15;
        const float* rp = src + row * 128 + kc * 8;
        float4 v0 = *(const float4*)rp;
        float4 v1 = *(const float4*)(rp + 4);
        uint4 o = make_uint4(rnepack(v0.x, v0.y), rnepack(v0.z, v0.w),
                             rnepack(v1.x, v1.y), rnepack(v1.z, v1.w));
        int off = row * 256 + ((kc * 16) ^ ((row & 7) << 4));
        *(uint4*)((char*)A + off) = o;
    }
}

__device__ __forceinline__ void stageA_bf16(const ushort* __restrict__ hsrc,
                                            const ushort* __restrict__ lsrc,
                                            ushort* Ahi, ushort* Alo, int tid) {
    #pragma unroll
    for (int i = 0; i < 4; ++i) {
        int f8  = i * 256 + tid;
        int row = f8 >> 4;
        int kc  = f8 & 15;
        uint4 hv = *(const uint4*)((const char*)hsrc + (size_t)(row * 128 + kc * 8) * 2);
        uint4 lv = *(const uint4*)((const char*)lsrc + (size_t)(row * 128 + kc * 8) * 2);
        int off = row * 256 + ((kc * 16) ^ ((row & 7) << 4));
        *(uint4*)((char*)Ahi + off) = hv;
        *(uint4*)((char*)Alo + off) = lv;
    }
}

// A-fragment read: lane holds A[row = mt*16 + (l&15)][k = kk*32 + (l>>4)*8 + 0..7]
__device__ __forceinline__ bf16x8 ldA(const ushort* A, int mt, int kk, int lane) {
    int row = mt * 16 + (lane & 15);
    int kb  = kk * 64 + ((lane >> 4) << 4);   // byte offset within row
    int off = row * 256 + (kb ^ ((row & 7) << 4));
    return *(const bf16x8*)((const char*)A + off);
}

// ---------------------------------------------------------------------------
// Weight packing
// ---------------------------------------------------------------------------
// Wq: linear pack to bf16 hi, pre-scaled by 1/sqrt(P)=0.25 (exact, pow2)
__global__ __launch_bounds__(256) void pack_wq(
    const float* __restrict__ src, ushort* __restrict__ dh, int n4)
{
    int i = blockIdx.x * 256 + threadIdx.x;
    if (i >= n4) return;
    float4 v = ((const float4*)src)[i];
    ((uint2*)dh)[i] = make_uint2(rnepack(v.x * 0.25f, v.y * 0.25f),
                                 rnepack(v.z * 0.25f, v.w * 0.25f));
}

// Wk/Wv [h,e,p] -> [h*16+p][e] bf16 hi
__global__ __launch_bounds__(256) void pack_kvw(
    const float* __restrict__ src, ushort* __restrict__ dh)
{
    int idx = blockIdx.x * 256 + threadIdx.x;    // 16384
    int hp = idx >> 7, e = idx & 127;
    int h = hp >> 4, p = hp & 15;
    dh[idx] = (ushort)rne1(src[(h * 128 + e) * 16 + p]);
}

// Wo [c,e,f] -> [c*128+f][e] hi/lo via LDS transpose
__global__ __launch_bounds__(256) void pack_wo(
    const float* __restrict__ Wo, ushort* __restrict__ dh, ushort* __restrict__ dl)
{
    __shared__ float t[32][129];
    const int tid = threadIdx.x;
    const int c = blockIdx.y, ec = blockIdx.x * 32;
    #pragma unroll
    for (int i = 0; i < 16; ++i) {
        int idx = i * 256 + tid;                 // 4096 = 32*128
        int e = idx >> 7, f = idx & 127;
        t[e][f] = Wo[((size_t)(c * 128) + ec + e) * 128 + f];
    }
    __syncthreads();
    #pragma unroll
    for (int i = 0; i < 8; ++i) {
        int o2 = i * 256 + tid;                  // 2048 pairs
        int f = o2 >> 4, e2 = o2 & 15;
        uint hh, ll;
        cvt2(t[2 * e2][f], t[2 * e2 + 1][f], hh, ll);
        size_t oo = ((size_t)(c * 128 + f)) * 128 + ec + 2 * e2;   // even
        *(uint*)((char*)dh + oo * 2) = hh;
        *(uint*)((char*)dl + oo * 2) = ll;
    }
}

// ---------------------------------------------------------------------------
// Fused K/V/Q projection, pure bf16 MFMA. Block = 64 x-rows (fixed b,c).
// N = 384 cols: [0,128) = K(h,p), [128,256) = V, [256,384) = Q.
// Wave w owns 6 n-tiles (96 cols). Outputs bf16, layout [bsh][c][p].
// ---------------------------------------------------------------------------
__global__ __launch_bounds__(256) void kvq_mfma(
    const float* __restrict__ x,
    const ushort* __restrict__ wk, const ushort* __restrict__ wv,
    const ushort* __restrict__ wq,
    ushort* __restrict__ kb, ushort* __restrict__ vb, ushort* __restrict__ qb)
{
    __shared__ __align__(16) ushort Ah[64 * 128];
    const int tid  = threadIdx.x;
    const int row0 = blockIdx.x * 64;           // = b*16384 + c*128 + s0
    const int c    = (row0 >> 7) & 127;
    stageA_hi(x + (size_t)row0 * 128, Ah, tid);
    __syncthreads();

    const int lane = tid & 63;
    const int w    = tid >> 6;
    const int bcol = lane & 15;
    const int bkg  = (lane >> 4) * 8;

    f32x4 zed; zed[0]=0.f; zed[1]=0.f; zed[2]=0.f; zed[3]=0.f;
    f32x4 acc[4][6];
    #pragma unroll
    for (int i = 0; i < 4; ++i)
        #pragma unroll
        for (int j = 0; j < 6; ++j) acc[i][j] = zed;

    #pragma unroll
    for (int kk = 0; kk < 4; ++kk) {
        bf16x8 Bh[6];
        #pragma unroll
        for (int j = 0; j < 6; ++j) {
            int nf  = w * 96 + j * 16 + bcol;       // full column
            int tgt = nf >> 7;                      // 0=K 1=V 2=Q (wave-uniform)
            int cf  = nf & 127;
            size_t eo;
            if (tgt == 2) eo = ((size_t)((cf >> 4) * 2048 + c * 16 + (cf & 15))) * 128;
            else          eo = (size_t)cf * 128;
            const ushort* bp = (tgt == 0) ? wk : (tgt == 1) ? wv : wq;
            Bh[j] = *(const bf16x8*)(bp + eo + kk * 32 + bkg);
        }
        #pragma unroll
        for (int mt = 0; mt < 4; ++mt) {
            bf16x8 ah = ldA(Ah, mt, kk, lane);
            #pragma unroll
            for (int j = 0; j < 6; ++j)
                acc[mt][j] = mfma16(ah, Bh[j], acc[mt][j]);
        }
    }

    const int mrow = (lane >> 4) * 4;
    const int b = row0 >> 14;
    #pragma unroll
    for (int mt = 0; mt < 4; ++mt) {
        #pragma unroll
        for (int reg = 0; reg < 4; ++reg) {
            int gr = row0 + mt * 16 + mrow + reg;
            int s  = gr & 127;
            size_t rb = (size_t)((b * 128 + s) * 8) * 2048 + c * 16;
            #pragma unroll
            for (int j = 0; j < 6; ++j) {
                int nf = w * 96 + j * 16 + bcol;
                int tgt = nf >> 7;
                int cf  = nf & 127;
                ushort* op = (tgt == 0) ? kb : (tgt == 1) ? vb : qb;
                op[rb + (size_t)(cf >> 4) * 2048 + (cf & 15)] =
                    (ushort)rne1(acc[mt][j][reg]);
            }
        }
    }
}

// ---------------------------------------------------------------------------
// Attention, all-bf16 MFMA. Block = (b,s,h), 4 waves, ONE barrier.
// S^T = mfma32(A=K, B=Q): lane col = c -> softmax in-lane + shfl_xor(32).
// P (bf16) -> swizzled LDS; PV = mfma16(A=P, B=V^T from LDS).
// q pre-scaled by 0.25 via Wq pack.
// ---------------------------------------------------------------------------
__global__ __launch_bounds__(256) void attn_mfma(
    const ushort* __restrict__ qb, const ushort* __restrict__ kb,
    const ushort* __restrict__ vb, ushort* __restrict__ ohi, ushort* __restrict__ olo)
{
    __shared__ __align__(16) ushort VT[16][136];    // V^T (bf16), 2-way-free reads
    __shared__ __align__(16) ushort Pw[4][4096];    // per-wave P, XOR-swizzled
    const int tid  = threadIdx.x;
    const int idx  = blockIdx.x;                    // = (b*S+s)*H + h
    const size_t base = (size_t)idx * 2048;

    // ---- stage V^T (pure copy: v already bf16) ----
    {
        int d = tid >> 1, p0 = (tid & 1) * 8;
        uint4 vv = *(const uint4*)(vb + base + d * 16 + p0);
        const ushort* sv = (const ushort*)&vv;
        #pragma unroll
        for (int j = 0; j < 8; ++j) VT[p0 + j][d] = sv[j];
    }

    // ---- Q/K fragments: direct bf16 loads, no conversion ----
    const int lane = tid & 63;
    const int w    = tid >> 6;        // wave = c-tile
    const int cg   = lane & 31;
    const int ph   = (lane >> 5) * 8; // k(=p)-half
    bf16x8 Q = *(const bf16x8*)(qb + base + (w * 32 + cg) * 16 + ph);
    bf16x8 K[4];
    #pragma unroll
    for (int dt = 0; dt < 4; ++dt)
        K[dt] = *(const bf16x8*)(kb + base + (dt * 32 + cg) * 16 + ph);

    // ---- scores S^T: acc[dt] covers d = 32dt+row, c = 32w + cg ----
    f32x16 S[4];
    #pragma unroll
    for (int dt = 0; dt < 4; ++dt)
        #pragma unroll
        for (int r = 0; r < 16; ++r) S[dt][r] = 0.f;
    __builtin_amdgcn_s_setprio(1);
    #pragma unroll
    for (int dt = 0; dt < 4; ++dt) S[dt] = mfma32(K[dt], Q, S[dt]);
    __builtin_amdgcn_s_setprio(0);

    // ---- softmax over d: 64 in-lane + lane-pair exchange ----
    float m = -1e30f;
    #pragma unroll
    for (int dt = 0; dt < 4; ++dt)
        #pragma unroll
        for (int r = 0; r < 16; ++r) m = fmaxf(m, S[dt][r]);
    m = fmaxf(m, __shfl_xor(m, 32));
    float sum = 0.f;
    #pragma unroll
    for (int dt = 0; dt < 4; ++dt)
        #pragma unroll
        for (int r = 0; r < 16; ++r) { S[dt][r] = __expf(S[dt][r] - m); sum += S[dt][r]; }
    sum += __shfl_xor(sum, 32);
    const float inv = 1.0f / sum;

    // ---- pack P to LDS: b64 writes, swizzle byte ^= (row&15)<<3 (2-way) ----
    char* pwb = (char*)&Pw[w][0];
    const int hib = (lane >> 5) * 8;        // byte offset of this lane's 4-elem group
    const int rsw = (cg & 15) << 3;
    #pragma unroll
    for (int dt = 0; dt < 4; ++dt) {
        #pragma unroll
        for (int g = 0; g < 4; ++g) {
            uint u0 = rnepack(S[dt][4*g+0] * inv, S[dt][4*g+1] * inv);
            uint u1 = rnepack(S[dt][4*g+2] * inv, S[dt][4*g+3] * inv);
            int cb = dt * 64 + g * 16 + hib;
            *(uint2*)(pwb + cg * 256 + (cb ^ rsw)) = make_uint2(u0, u1);
        }
    }
    __syncthreads();   // VT (cross-wave) + Pw visibility

    // ---- PV: O[c 32][p 16] per wave ----
    f32x4 O[2];
    #pragma unroll
    for (int mt = 0; mt < 2; ++mt) { O[mt][0]=0.f; O[mt][1]=0.f; O[mt][2]=0.f; O[mt][3]=0.f; }
    const int pcol = lane & 15;
    const int dgb  = (lane >> 4) * 16;      // byte offset of d-group
    const int rs   = pcol << 3;             // (row&15) == pcol for both mt
    #pragma unroll
    for (int ks = 0; ks < 4; ++ks) {
        bf16x8 Bv = *(const bf16x8*)((const char*)&VT[0][0] + pcol * 272 + ks * 64 + dgb);
        #pragma unroll
        for (int mt = 0; mt < 2; ++mt) {
            int rowb = (mt * 16 + pcol) * 256;
            int cb0  = ks * 64 + dgb;
            uint2 a0 = *(const uint2*)(pwb + rowb + (cb0 ^ rs));
            uint2 a1 = *(const uint2*)(pwb + rowb + ((cb0 + 8) ^ rs));
            uint4 av = make_uint4(a0.x, a0.y, a1.x, a1.y);
            __builtin_amdgcn_s_setprio(1);
            O[mt] = mfma16(__builtin_bit_cast(bf16x8, av), Bv, O[mt]);
            __builtin_amdgcn_s_setprio(0);
        }
    }

    // ---- epilogue: o -> [B,C,S,E] bf16 hi/lo planes ----
    const int h  = idx & 7;
    const int bs = idx >> 3;
    const int b  = bs >> 7, s = bs & 127;
    const int rg = (lane >> 4) * 4;
    #pragma unroll
    for (int mt = 0; mt < 2; ++mt) {
        #pragma unroll
        for (int reg = 0; reg < 4; ++reg) {
            int cc = w * 32 + mt * 16 + rg + reg;
            uint hh, ll; cvt_hilo(O[mt][reg], hh, ll);
            size_t ob = ((size_t)(b * 128 + cc) * 128 + s) * 128 + h * 16 + pcol;
            ohi[ob] = (ushort)hh;
            olo[ob] = (ushort)ll;
        }
    }
}

// ---------------------------------------------------------------------------
// Output mixing, split-bf16 MFMA (precision-critical final stage; unchanged).
// ---------------------------------------------------------------------------
__global__ __launch_bounds__(256) void out_mfma(
    const ushort* __restrict__ ohi, const ushort* __restrict__ olo,
    const ushort* __restrict__ wohi, const ushort* __restrict__ wolo,
    float* __restrict__ out)
{
    __shared__ __align__(16) ushort Ahi[64 * 128];
    __shared__ __align__(16) ushort Alo[64 * 128];
    const int tid  = threadIdx.x;
    const int c    = blockIdx.y;
    const int row0 = blockIdx.x * 64;
    const int b0 = row0 >> 7, s0 = row0 & 127;
    const size_t gbase = ((size_t)(b0 * 128 + c) * 128 + s0) * 128;
    stageA_bf16(ohi + gbase, olo + gbase, Ahi, Alo, tid);
    __syncthreads();

    const int lane = tid & 63;
    const int w    = tid >> 6;
    const int bcol = lane & 15;
    const int bkg  = (lane >> 4) * 8;

    f32x4 zed; zed[0]=0.f; zed[1]=0.f; zed[2]=0.f; zed[3]=0.f;
    f32x4 acc[4][2];
    #pragma unroll
    for (int i = 0; i < 4; ++i) { acc[i][0] = zed; acc[i][1] = zed; }

    #pragma unroll
    for (int kk = 0; kk < 4; ++kk) {
        bf16x8 Bh[2], Bl[2];
        #pragma unroll
        for (int j = 0; j < 2; ++j) {
            int f = w * 32 + j * 16 + bcol;
            size_t eo = ((size_t)(c * 128 + f)) * 128 + kk * 32 + bkg;
            Bh[j] = *(const bf16x8*)(wohi + eo);
            Bl[j] = *(const bf16x8*)(wolo + eo);
        }
        #pragma unroll
        for (int mt = 0; mt < 4; ++mt) {
            bf16x8 ah = ldA(Ahi, mt, kk, lane);
            bf16x8 al = ldA(Alo, mt, kk, lane);
            #pragma unroll
            for (int j = 0; j < 2; ++j) {
                acc[mt][j] = mfma16(ah, Bh[j], acc[mt][j]);
                acc[mt][j] = mfma16(ah, Bl[j], acc[mt][j]);
                acc[mt][j] = mfma16(al, Bh[j], acc[mt][j]);
            }
        }
    }
    const int mrow = (lane >> 4) * 4;
    #pragma unroll
    for (int mt = 0; mt < 4; ++mt) {
        #pragma unroll
        for (int reg = 0; reg < 4; ++reg) {
            int m = mt * 16 + mrow + reg;
            #pragma unroll
            for (int j = 0; j < 2; ++j) {
                int f = w * 32 + j * 16 + bcol;
                out[gbase + (size_t)m * 128 + f] = acc[mt][j][reg];
            }
        }
    }
}

// Sentinel: unambiguous signal that ws_size was too small.
__global__ void sentinel_kernel(float* out, int n) {
    int i = blockIdx.x * 256 + threadIdx.x;
    if (i < n) out[i] = 1.0e6f;
}

extern "C" void kernel_launch(void* const* d_in, const int* in_sizes, int n_in,
                              void* d_out, int out_size, void* d_ws, size_t ws_size,
                              hipStream_t stream)
{
    const float* x  = (const float*)d_in[0];
    const float* Wq = (const float*)d_in[1];
    const float* Wk = (const float*)d_in[2];
    const float* Wv = (const float*)d_in[3];
    const float* Wo = (const float*)d_in[4];
    float* out = (float*)d_out;

    const size_t CH = (size_t)CHUNK;
    ushort* qbuf = (ushort*)d_ws;             // bf16 planes, 32 MiB each
    ushort* kbuf = qbuf + CH;
    ushort* vbuf = kbuf + CH;
    ushort* ohi  = vbuf + CH;
    ushort* olo  = ohi + CH;
    ushort* wq   = olo + CH;                  // 4 MiB
    ushort* wk   = wq + WQ_ELEMS;
    ushort* wv   = wk + WKV_ELEMS;
    ushort* wohi = wv + WKV_ELEMS;            // 4 MiB
    ushort* wolo = wohi + WO_ELEMS;           // 4 MiB

    const size_t need = (5 * CH + (size_t)WQ_ELEMS + 2 * (size_t)WKV_ELEMS
                         + 2 * (size_t)WO_ELEMS) * sizeof(ushort);   // ~180 MiB
    if (ws_size < need) {
        sentinel_kernel<<<(out_size + 255) / 256, 256, 0, stream>>>(out, out_size);
        return;
    }

    pack_wq<<<WQ_ELEMS / 4 / 256, 256, 0, stream>>>(Wq, wq, WQ_ELEMS / 4);
    pack_kvw<<<WKV_ELEMS / 256, 256, 0, stream>>>(Wk, wk);
    pack_kvw<<<WKV_ELEMS / 256, 256, 0, stream>>>(Wv, wv);
    pack_wo<<<dim3(4, NC), 256, 0, stream>>>(Wo, wohi, wolo);

    kvq_mfma<<<NROWS / 64, 256, 0, stream>>>(x, wk, wv, wq, kbuf, vbuf, qbuf);
    attn_mfma<<<BSROWS * NH, 256, 0, stream>>>(qbuf, kbuf, vbuf, ohi, olo);
    out_mfma<<<dim3(BSROWS / 64, NC), 256, 0, stream>>>(ohi, olo, wohi, wolo, out);
}